// Round 5
// baseline (175.915 us; speedup 1.0000x reference)
//
#include <hip/hip_runtime.h>

typedef __attribute__((ext_vector_type(8))) short  s8v;   // 8 bf16 (4 VGPR)
typedef __attribute__((ext_vector_type(4))) float  f4v;   // MFMA accumulator

#define N_   4096
#define N2   8192
#define D_   256
#define NIDS 1000
#define LCAP 32      // max members per class (Poisson(4.1) max ~15)

constexpr float INV_TEMP   = 10.0f;                 // 1/0.1
constexpr float K_LOG2     = 14.426950408889634f;   // 10 * log2(e)
constexpr float LN2F       = 0.6931471805599453f;
constexpr float NEGINF     = -1e30f;

__device__ __forceinline__ const float* frow(const float* f, int r) {
    return f + (size_t)(r & (N_ - 1)) * (2 * D_) + (size_t)((r >> 12) * D_);
}

__device__ __forceinline__ ushort f2bf(float x) {
    unsigned u = __float_as_uint(x);
    return (ushort)((u + 0x7FFFu + ((u >> 16) & 1u)) >> 16);   // RNE
}
__device__ __forceinline__ float bf2f(ushort b) {
    return __uint_as_float(((unsigned)b) << 16);
}

// ---------- convert: f32 [N,2,D] -> hi/lo bf16 [8192][256] ----------
__global__ __launch_bounds__(256) void convertK(const float* __restrict__ feat,
                                                ushort* __restrict__ fhi,
                                                ushort* __restrict__ flo) {
    int t = blockIdx.x * 256 + threadIdx.x;
    int r = t >> 5, g = t & 31;
    const float* src = frow(feat, r) + g * 8;
    float4 v0 = *(const float4*)src;
    float4 v1 = *(const float4*)(src + 4);
    float x[8] = {v0.x, v0.y, v0.z, v0.w, v1.x, v1.y, v1.z, v1.w};
    s8v h8, l8;
    #pragma unroll
    for (int i = 0; i < 8; ++i) {
        ushort h = f2bf(x[i]);
        h8[i] = (short)h;
        l8[i] = (short)f2bf(x[i] - bf2f(h));
    }
    *(s8v*)(fhi + (size_t)r * D_ + g * 8) = h8;
    *(s8v*)(flo + (size_t)r * D_ + g * 8) = l8;
}

// ---------- build per-class member lists (deterministic, ascending) ----------
__global__ __launch_bounds__(256) void buildLists(const int* __restrict__ label,
                                                  int* __restrict__ lists) {
    int cls  = blockIdx.x * 4 + (threadIdx.x >> 6);   // 250 blocks -> 1000 classes
    int lane = threadIdx.x & 63;
    int* Lp = lists + (size_t)cls * (LCAP + 1);
    int cnt = 0;
    for (int jj = 0; jj < N_; jj += 64) {
        unsigned long long mk = __ballot(label[jj + lane] == cls);
        while (mk) {
            int b = __ffsll((unsigned long long)mk) - 1;
            mk &= mk - 1;
            if (lane == 0 && cnt < LCAP) Lp[1 + cnt] = jj + b;
            ++cnt;
        }
    }
    if (lane == 0) Lp[0] = (cnt < LCAP) ? cnt : LCAP;
}

// ---------- Phase A: upper-tri 128x128 split-bf16 MFMA, prefetched staging ----------
__global__ __launch_bounds__(256) void phaseA(const ushort* __restrict__ fhi,
                                              const ushort* __restrict__ flo,
                                              const int* __restrict__ label,
                                              float2* __restrict__ partial) {
    __shared__ ushort panels[4][128][64];   // Ahi | Alo | Bhi | Blo = 64 KB
    char* base = (char*)panels;

    const int tid  = threadIdx.x;
    const int lane = tid & 63;
    const int w    = tid >> 6;
    const int wr   = w >> 1, wc = w & 1;

    // XCD swizzle (2080 = 8*260, bijective) then upper-tri decode
    int idx = (blockIdx.x & 7) * 260 + (blockIdx.x >> 3);
    int rt = 0, rem = idx;
    while (rem >= 64 - rt) { rem -= 64 - rt; ++rt; }
    const int ct = rt + rem;
    const bool offdiag = (ct != rt);
    const int rowBase = rt * 128, colBase = ct * 128;

    f4v acc[4][4];
    #pragma unroll
    for (int i = 0; i < 4; ++i)
        #pragma unroll
        for (int j = 0; j < 4; ++j) acc[i][j] = (f4v){0.f, 0.f, 0.f, 0.f};

    const int skg = tid & 7;
    const int sr0 = tid >> 3;

    // per-q constants
    int srow[4], soff[4];
    size_t gaBase[4], gbBase[4];
    #pragma unroll
    for (int q = 0; q < 4; ++q) {
        int row = q * 32 + sr0;
        srow[q] = row;
        soff[q] = row * 128 + ((skg * 16) ^ ((row & 7) << 4));
        gaBase[q] = (size_t)(rowBase + row) * D_ + skg * 8;
        gbBase[q] = (size_t)(colBase + row) * D_ + skg * 8;
    }

    // prefetch chunk 0
    s8v pre[4][4];
    #pragma unroll
    for (int q = 0; q < 4; ++q) {
        pre[q][0] = *(const s8v*)(fhi + gaBase[q]);
        pre[q][1] = *(const s8v*)(flo + gaBase[q]);
        pre[q][2] = *(const s8v*)(fhi + gbBase[q]);
        pre[q][3] = *(const s8v*)(flo + gbBase[q]);
    }

    for (int kc = 0; kc < 4; ++kc) {
        __syncthreads();
        #pragma unroll
        for (int q = 0; q < 4; ++q) {
            *(s8v*)(base + soff[q])         = pre[q][0];
            *(s8v*)(base + 16384 + soff[q]) = pre[q][1];
            *(s8v*)(base + 32768 + soff[q]) = pre[q][2];
            *(s8v*)(base + 49152 + soff[q]) = pre[q][3];
        }
        __syncthreads();

        if (kc < 3) {   // issue next chunk's loads; they fly under the MFMAs
            const int kB = (kc + 1) * 64;
            #pragma unroll
            for (int q = 0; q < 4; ++q) {
                pre[q][0] = *(const s8v*)(fhi + gaBase[q] + kB);
                pre[q][1] = *(const s8v*)(flo + gaBase[q] + kB);
                pre[q][2] = *(const s8v*)(fhi + gbBase[q] + kB);
                pre[q][3] = *(const s8v*)(flo + gbBase[q] + kB);
            }
        }

        #pragma unroll
        for (int ks = 0; ks < 2; ++ks) {
            const int kb = ks * 64 + (lane >> 4) * 16;
            s8v ah[4], al[4], bh[4], bl[4];
            #pragma unroll
            for (int rf = 0; rf < 4; ++rf) {
                int row = wr * 64 + rf * 16 + (lane & 15);
                int off = row * 128 + (kb ^ ((row & 7) << 4));
                ah[rf] = *(const s8v*)(base + off);
                al[rf] = *(const s8v*)(base + 16384 + off);
            }
            #pragma unroll
            for (int cf = 0; cf < 4; ++cf) {
                int col = wc * 64 + cf * 16 + (lane & 15);
                int off = col * 128 + (kb ^ ((col & 7) << 4));
                bh[cf] = *(const s8v*)(base + 32768 + off);
                bl[cf] = *(const s8v*)(base + 49152 + off);
            }
            __builtin_amdgcn_s_setprio(1);
            #pragma unroll
            for (int rf = 0; rf < 4; ++rf)
                #pragma unroll
                for (int cf = 0; cf < 4; ++cf) {
                    acc[rf][cf] = __builtin_amdgcn_mfma_f32_16x16x32_bf16(ah[rf], bh[cf], acc[rf][cf], 0, 0, 0);
                    acc[rf][cf] = __builtin_amdgcn_mfma_f32_16x16x32_bf16(al[rf], bh[cf], acc[rf][cf], 0, 0, 0);
                    acc[rf][cf] = __builtin_amdgcn_mfma_f32_16x16x32_bf16(ah[rf], bl[cf], acc[rf][cf], 0, 0, 0);
                }
            __builtin_amdgcn_s_setprio(0);
        }
    }

    // ================= epilogue (log2 domain) =================
    __syncthreads();

    float* fsm    = (float*)base;
    float* rowm   = fsm;                       // [128][33]
    float* colm   = fsm + 4224;                // [128][9]
    float* mrowS  = fsm + 4224 + 1152;         // [128]
    float* mcolS  = mrowS + 128;               // [128]
    float* rows_s = mcolS + 128;               // [128][33]
    float* cols_s = rows_s + 4224;             // [128][9]

    const int grp32 = wc * 16 + (lane & 15);
    const int grp8  = wr * 4 + (lane >> 4);
    int rloc[16], cloc[4];
    int rowlab[16], collab[4];
    #pragma unroll
    for (int rf = 0; rf < 4; ++rf)
        #pragma unroll
        for (int rg = 0; rg < 4; ++rg) {
            int i = rf * 4 + rg;
            rloc[i] = wr * 64 + rf * 16 + (lane >> 4) * 4 + rg;
            rowlab[i] = label[(rowBase + rloc[i]) & (N_ - 1)];
        }
    #pragma unroll
    for (int cf = 0; cf < 4; ++cf) {
        cloc[cf] = wc * 64 + cf * 16 + (lane & 15);
        collab[cf] = label[(colBase + cloc[cf]) & (N_ - 1)];
    }

    // masked log2-logits in place
    #pragma unroll
    for (int rf = 0; rf < 4; ++rf)
        #pragma unroll
        for (int cf = 0; cf < 4; ++cf)
            #pragma unroll
            for (int rg = 0; rg < 4; ++rg) {
                float v = acc[rf][cf][rg] * K_LOG2;
                acc[rf][cf][rg] = (collab[cf] == rowlab[rf * 4 + rg]) ? NEGINF : v;
            }

    #pragma unroll
    for (int rf = 0; rf < 4; ++rf)
        #pragma unroll
        for (int rg = 0; rg < 4; ++rg) {
            int i = rf * 4 + rg;
            float m = fmaxf(fmaxf(acc[rf][0][rg], acc[rf][1][rg]),
                            fmaxf(acc[rf][2][rg], acc[rf][3][rg]));
            rowm[rloc[i] * 33 + grp32] = m;
        }
    if (offdiag) {
        #pragma unroll
        for (int cf = 0; cf < 4; ++cf) {
            float m = NEGINF;
            #pragma unroll
            for (int rf = 0; rf < 4; ++rf)
                #pragma unroll
                for (int rg = 0; rg < 4; ++rg)
                    m = fmaxf(m, acc[rf][cf][rg]);
            colm[cloc[cf] * 9 + grp8] = m;
        }
    }
    __syncthreads();
    if (tid < 128) {
        float m = NEGINF;
        #pragma unroll
        for (int g = 0; g < 32; ++g) m = fmaxf(m, rowm[tid * 33 + g]);
        mrowS[tid] = m;
        if (offdiag) {
            float mc = NEGINF;
            #pragma unroll
            for (int g = 0; g < 8; ++g) mc = fmaxf(mc, colm[tid * 9 + g]);
            mcolS[tid] = mc;
        }
    }
    __syncthreads();

    float mr[16];
    #pragma unroll
    for (int i = 0; i < 16; ++i) mr[i] = mrowS[rloc[i]];
    float mcv[4];
    if (offdiag) {
        #pragma unroll
        for (int cf = 0; cf < 4; ++cf) mcv[cf] = mcolS[cloc[cf]];
    }

    float srl[16];
    #pragma unroll
    for (int i = 0; i < 16; ++i) srl[i] = 0.f;
    float scl[4] = {0.f, 0.f, 0.f, 0.f};
    #pragma unroll
    for (int rf = 0; rf < 4; ++rf)
        #pragma unroll
        for (int cf = 0; cf < 4; ++cf)
            #pragma unroll
            for (int rg = 0; rg < 4; ++rg) {
                int i = rf * 4 + rg;
                float v = acc[rf][cf][rg];
                srl[i] += exp2f(v - mr[i]);
                if (offdiag) scl[cf] += exp2f(v - mcv[cf]);
            }
    #pragma unroll
    for (int i = 0; i < 16; ++i) rows_s[rloc[i] * 33 + grp32] = srl[i];
    if (offdiag) {
        #pragma unroll
        for (int cf = 0; cf < 4; ++cf) cols_s[cloc[cf] * 9 + grp8] = scl[cf];
    }
    __syncthreads();
    if (tid < 128) {
        float s = 0.f;
        #pragma unroll
        for (int g = 0; g < 32; ++g) s += rows_s[tid * 33 + g];
        partial[(size_t)ct * N2 + rowBase + tid] = make_float2(mrowS[tid], s);
        if (offdiag) {
            float s2 = 0.f;
            #pragma unroll
            for (int g = 0; g < 8; ++g) s2 += cols_s[tid * 9 + g];
            partial[(size_t)rt * N2 + colBase + tid] = make_float2(mcolS[tid], s2);
        }
    }
}

// ---------- merge col-tile partials -> c_id2[row] (log2 domain) ----------
__global__ __launch_bounds__(256) void mergeC(const float2* __restrict__ partial,
                                              float* __restrict__ cid) {
    int row = blockIdx.x * 256 + threadIdx.x;
    float m = NEGINF, s = 0.f;
    for (int ct = 0; ct < 64; ++ct) {
        float2 p = partial[(size_t)ct * N2 + row];
        float nm = fmaxf(m, p.x);
        s = s * exp2f(m - nm) + p.y * exp2f(p.x - nm);
        m = nm;
    }
    cid[row] = m + __log2f(s);
}

// ---------- Phase B: class-list walk, lane-parallel CE ----------
__global__ __launch_bounds__(512) void phaseB(const float* __restrict__ feat,
                                              const int* __restrict__ label,
                                              const int* __restrict__ camid,
                                              const int* __restrict__ lists,
                                              const float* __restrict__ cid_,
                                              float* __restrict__ rowloss) {
    __shared__ float listA[8][64];
    __shared__ int   listF[8][64];

    const int tid = threadIdx.x, lane = tid & 63, w = tid >> 6;
    const int row = blockIdx.x * 8 + w;
    const int rl = label[row & (N_ - 1)];
    const int rc = camid[row & (N_ - 1)];
    const float cid = cid_[row] * LN2F;       // -> natural log
    const float* fi = frow(feat, row);
    float4 fi4 = *(const float4*)(fi + lane * 4);

    const int* Lp = lists + (size_t)rl * (LCAP + 1);
    const int nmem = Lp[0];

    int cnt = 0;
    for (int e = 0; e < nmem; ++e) {
        int j = Lp[1 + e];
        int cm = (camid[j] == rc) ? 1 : 0;
        #pragma unroll
        for (int h = 0; h < 2; ++h) {
            int c = j + h * N_;
            if (c == row) continue;          // wave-uniform
            const float* fc = frow(feat, c);
            float4 v = *(const float4*)(fc + lane * 4);
            float p = fi4.x * v.x + fi4.y * v.y + fi4.z * v.z + fi4.w * v.w;
            #pragma unroll
            for (int off = 32; off >= 1; off >>= 1) p += __shfl_xor(p, off);
            if (lane == 0) { listA[w][cnt] = p * INV_TEMP; listF[w][cnt] = cm; }
            ++cnt;
        }
    }

    float a_e = (lane < cnt) ? listA[w][lane] : NEGINF;
    int   f_e = (lane < cnt) ? listF[w][lane] : 1;

    // extras LSE (label-match, cam-mismatch)
    float xa = (f_e == 0) ? a_e : NEGINF;
    float mx = xa;
    #pragma unroll
    for (int off = 32; off >= 1; off >>= 1) mx = fmaxf(mx, __shfl_xor(mx, off));
    float xe = (f_e == 0) ? __expf(xa - mx) : 0.f;
    #pragma unroll
    for (int off = 32; off >= 1; off >>= 1) xe += __shfl_xor(xe, off);
    float ccam;
    if (xe > 0.f) {
        float xl = mx + __logf(xe);
        float d = xl - cid;
        ccam = (d <= 0.f) ? cid + log1pf(__expf(d)) : xl + log1pf(__expf(-d));
    } else {
        ccam = cid;
    }

    float ti = cid - a_e;
    float termid = (ti <= 0.f) ? log1pf(__expf(ti)) : ti + log1pf(__expf(-ti));
    termid = (lane < cnt) ? termid : 0.f;
    float tc = ccam - a_e;
    float termcam = (tc <= 0.f) ? log1pf(__expf(tc)) : tc + log1pf(__expf(-tc));
    termcam = (lane < cnt && f_e) ? termcam : 0.f;
    #pragma unroll
    for (int off = 32; off >= 1; off >>= 1) {
        termid  += __shfl_xor(termid, off);
        termcam += __shfl_xor(termcam, off);
    }
    int ncam = __popcll(__ballot(lane < cnt && f_e));
    if (lane == 0)
        rowloss[row] = termid / (float)cnt + 0.5f * termcam / (float)ncam;
}

// ---------- Phase C: deterministic final reduce ----------
__global__ __launch_bounds__(256) void phaseC(const float* __restrict__ rowloss,
                                              float* __restrict__ out) {
    __shared__ float red[256];
    float s = 0.f;
    for (int i = threadIdx.x; i < N2; i += 256) s += rowloss[i];
    red[threadIdx.x] = s;
    __syncthreads();
    for (int w = 128; w > 0; w >>= 1) {
        if (threadIdx.x < w) red[threadIdx.x] += red[threadIdx.x + w];
        __syncthreads();
    }
    if (threadIdx.x == 0) out[0] = red[0] / (float)N2;
}

extern "C" void kernel_launch(void* const* d_in, const int* in_sizes, int n_in,
                              void* d_out, int out_size, void* d_ws, size_t ws_size,
                              hipStream_t stream) {
    const float* feat  = (const float*)d_in[0];
    const int*   label = (const int*)d_in[1];
    const int*   camid = (const int*)d_in[2];

    ushort* fhi = (ushort*)d_ws;                                  // 4 MB
    ushort* flo = fhi + (size_t)N2 * D_;                          // 4 MB
    float2* partial = (float2*)((char*)d_ws + 8u * 1024 * 1024);  // 4 MB
    float*  cid     = (float*)((char*)d_ws + 12u * 1024 * 1024);  // 32 KB
    float*  rowloss = cid + N2;                                   // 32 KB
    int*    lists   = (int*)(rowloss + N2);                       // 1000*33*4 B

    convertK<<<1024, 256, 0, stream>>>(feat, fhi, flo);
    buildLists<<<250, 256, 0, stream>>>(label, lists);
    phaseA<<<2080, 256, 0, stream>>>(fhi, flo, label, partial);
    mergeC<<<32, 256, 0, stream>>>(partial, cid);
    phaseB<<<1024, 512, 0, stream>>>(feat, label, camid, lists, cid, rowloss);
    phaseC<<<1, 256, 0, stream>>>(rowloss, (float*)d_out);
}

// Round 6
// 132.593 us; speedup vs baseline: 1.3267x; 1.3267x over previous
//
#include <hip/hip_runtime.h>

typedef __attribute__((ext_vector_type(8))) short  s8v;   // 8 bf16 (4 VGPR)
typedef __attribute__((ext_vector_type(4))) float  f4v;   // MFMA accumulator

#define N_   4096
#define N2   8192
#define D_   256
#define NIDS 1000
#define LCAP 32      // max members per class

constexpr float INV_TEMP   = 10.0f;                 // 1/0.1
constexpr float K_LOG2     = 14.426950408889634f;   // 10 * log2(e)
constexpr float LN2F       = 0.6931471805599453f;
constexpr float NEGINF     = -1e30f;

__device__ __forceinline__ const float* frow(const float* f, int r) {
    return f + (size_t)(r & (N_ - 1)) * (2 * D_) + (size_t)((r >> 12) * D_);
}

__device__ __forceinline__ ushort f2bf(float x) {
    unsigned u = __float_as_uint(x);
    return (ushort)((u + 0x7FFFu + ((u >> 16) & 1u)) >> 16);   // RNE
}
__device__ __forceinline__ float bf2f(ushort b) {
    return __uint_as_float(((unsigned)b) << 16);
}

// async 16B global -> LDS (linear dest: wave-uniform base + lane*16)
__device__ __forceinline__ void gload_lds16(const void* g, void* l) {
    __builtin_amdgcn_global_load_lds(
        (const __attribute__((address_space(1))) void*)g,
        (__attribute__((address_space(3))) void*)l, 16, 0, 0);
}

// ---------- fused: convert f32 -> hi/lo bf16  +  per-class member lists ----------
__global__ __launch_bounds__(256) void prepK(const float* __restrict__ feat,
                                             const int* __restrict__ label,
                                             ushort* __restrict__ fhi,
                                             ushort* __restrict__ flo,
                                             int* __restrict__ lists) {
    if (blockIdx.x < 1024) {
        int t = blockIdx.x * 256 + threadIdx.x;
        int r = t >> 5, g = t & 31;
        const float* src = frow(feat, r) + g * 8;
        float4 v0 = *(const float4*)src;
        float4 v1 = *(const float4*)(src + 4);
        float x[8] = {v0.x, v0.y, v0.z, v0.w, v1.x, v1.y, v1.z, v1.w};
        s8v h8, l8;
        #pragma unroll
        for (int i = 0; i < 8; ++i) {
            ushort h = f2bf(x[i]);
            h8[i] = (short)h;
            l8[i] = (short)f2bf(x[i] - bf2f(h));
        }
        *(s8v*)(fhi + (size_t)r * D_ + g * 8) = h8;
        *(s8v*)(flo + (size_t)r * D_ + g * 8) = l8;
    } else {
        int cls  = (blockIdx.x - 1024) * 4 + (threadIdx.x >> 6);   // 250 blocks
        int lane = threadIdx.x & 63;
        int* Lp = lists + (size_t)cls * (LCAP + 1);
        int cnt = 0;
        for (int jj = 0; jj < N_; jj += 64) {
            unsigned long long mk = __ballot(label[jj + lane] == cls);
            while (mk) {
                int b = __ffsll((unsigned long long)mk) - 1;
                mk &= mk - 1;
                if (lane == 0 && cnt < LCAP) Lp[1 + cnt] = jj + b;
                ++cnt;
            }
        }
        if (lane == 0) Lp[0] = (cnt < LCAP) ? cnt : LCAP;
    }
}

// ---------- Phase A: upper-tri 128x128 split-bf16 MFMA, DMA staging ----------
__global__ __launch_bounds__(256) void phaseA(const ushort* __restrict__ fhi,
                                              const ushort* __restrict__ flo,
                                              const int* __restrict__ label,
                                              float2* __restrict__ partial) {
    __shared__ ushort panels[4][128][64];   // Ahi | Alo | Bhi | Blo = 64 KB
    char* base = (char*)panels;

    const int tid  = threadIdx.x;
    const int lane = tid & 63;
    const int w    = tid >> 6;
    const int wr   = w >> 1, wc = w & 1;

    // XCD swizzle (2080 = 8*260, bijective) then upper-tri decode
    int idx = (blockIdx.x & 7) * 260 + (blockIdx.x >> 3);
    int rt = 0, rem = idx;
    while (rem >= 64 - rt) { rem -= 64 - rt; ++rt; }
    const int ct = rt + rem;
    const bool offdiag = (ct != rt);
    const int rowBase = rt * 128, colBase = ct * 128;

    f4v acc[4][4];
    #pragma unroll
    for (int i = 0; i < 4; ++i)
        #pragma unroll
        for (int j = 0; j < 4; ++j) acc[i][j] = (f4v){0.f, 0.f, 0.f, 0.f};

    // per-wave DMA staging setup: wave w owns panel w
    //   panel 0: A-hi  1: A-lo  2: B-hi  3: B-lo
    // linear LDS dest (base + lane*16) <=> pre-swizzled global source chunk
    const ushort* gsrc = (w & 1) ? flo : fhi;
    const int     prB  = (w < 2) ? rowBase : colBase;
    char*         lp   = base + w * 16384;
    const int  lrow  = lane >> 3;                       // row within 8-row stripe
    const size_t glane = (size_t)(prB + lrow) * D_ + (size_t)(((lane & 7) ^ lrow) << 3);

    for (int kc = 0; kc < 4; ++kc) {
        __syncthreads();                    // previous chunk's LDS reads done
        const ushort* gk = gsrc + glane + kc * 64;
        #pragma unroll
        for (int i = 0; i < 16; ++i)
            gload_lds16(gk + i * 8 * D_, lp + i * 1024);
        __syncthreads();                    // vmcnt(0) drained before barrier

        #pragma unroll
        for (int ks = 0; ks < 2; ++ks) {
            const int kb = ks * 64 + (lane >> 4) * 16;
            s8v ah[4], al[4], bh[4], bl[4];
            #pragma unroll
            for (int rf = 0; rf < 4; ++rf) {
                int row = wr * 64 + rf * 16 + (lane & 15);
                int off = row * 128 + (kb ^ ((row & 7) << 4));
                ah[rf] = *(const s8v*)(base + off);
                al[rf] = *(const s8v*)(base + 16384 + off);
            }
            #pragma unroll
            for (int cf = 0; cf < 4; ++cf) {
                int col = wc * 64 + cf * 16 + (lane & 15);
                int off = col * 128 + (kb ^ ((col & 7) << 4));
                bh[cf] = *(const s8v*)(base + 32768 + off);
                bl[cf] = *(const s8v*)(base + 49152 + off);
            }
            #pragma unroll
            for (int rf = 0; rf < 4; ++rf)
                #pragma unroll
                for (int cf = 0; cf < 4; ++cf) {
                    acc[rf][cf] = __builtin_amdgcn_mfma_f32_16x16x32_bf16(ah[rf], bh[cf], acc[rf][cf], 0, 0, 0);
                    acc[rf][cf] = __builtin_amdgcn_mfma_f32_16x16x32_bf16(al[rf], bh[cf], acc[rf][cf], 0, 0, 0);
                    acc[rf][cf] = __builtin_amdgcn_mfma_f32_16x16x32_bf16(ah[rf], bl[cf], acc[rf][cf], 0, 0, 0);
                }
        }
    }

    // ================= epilogue (log2 domain) =================
    __syncthreads();

    float* fsm    = (float*)base;
    float* rowm   = fsm;                       // [128][33]
    float* colm   = fsm + 4224;                // [128][9]
    float* mrowS  = fsm + 4224 + 1152;         // [128]
    float* mcolS  = mrowS + 128;               // [128]
    float* rows_s = mcolS + 128;               // [128][33]
    float* cols_s = rows_s + 4224;             // [128][9]

    const int grp32 = wc * 16 + (lane & 15);
    const int grp8  = wr * 4 + (lane >> 4);
    int rloc[16], cloc[4];
    int rowlab[16], collab[4];
    #pragma unroll
    for (int rf = 0; rf < 4; ++rf)
        #pragma unroll
        for (int rg = 0; rg < 4; ++rg) {
            int i = rf * 4 + rg;
            rloc[i] = wr * 64 + rf * 16 + (lane >> 4) * 4 + rg;
            rowlab[i] = label[(rowBase + rloc[i]) & (N_ - 1)];
        }
    #pragma unroll
    for (int cf = 0; cf < 4; ++cf) {
        cloc[cf] = wc * 64 + cf * 16 + (lane & 15);
        collab[cf] = label[(colBase + cloc[cf]) & (N_ - 1)];
    }

    // masked log2-logits in place (positives/diag -> -1e30)
    #pragma unroll
    for (int rf = 0; rf < 4; ++rf)
        #pragma unroll
        for (int cf = 0; cf < 4; ++cf)
            #pragma unroll
            for (int rg = 0; rg < 4; ++rg) {
                float v = acc[rf][cf][rg] * K_LOG2;
                acc[rf][cf][rg] = (collab[cf] == rowlab[rf * 4 + rg]) ? NEGINF : v;
            }

    #pragma unroll
    for (int rf = 0; rf < 4; ++rf)
        #pragma unroll
        for (int rg = 0; rg < 4; ++rg) {
            int i = rf * 4 + rg;
            float m = fmaxf(fmaxf(acc[rf][0][rg], acc[rf][1][rg]),
                            fmaxf(acc[rf][2][rg], acc[rf][3][rg]));
            rowm[rloc[i] * 33 + grp32] = m;
        }
    if (offdiag) {
        #pragma unroll
        for (int cf = 0; cf < 4; ++cf) {
            float m = NEGINF;
            #pragma unroll
            for (int rf = 0; rf < 4; ++rf)
                #pragma unroll
                for (int rg = 0; rg < 4; ++rg)
                    m = fmaxf(m, acc[rf][cf][rg]);
            colm[cloc[cf] * 9 + grp8] = m;
        }
    }
    __syncthreads();
    if (tid < 128) {
        float m = NEGINF;
        #pragma unroll
        for (int g = 0; g < 32; ++g) m = fmaxf(m, rowm[tid * 33 + g]);
        mrowS[tid] = m;
        if (offdiag) {
            float mc = NEGINF;
            #pragma unroll
            for (int g = 0; g < 8; ++g) mc = fmaxf(mc, colm[tid * 9 + g]);
            mcolS[tid] = mc;
        }
    }
    __syncthreads();

    float mr[16];
    #pragma unroll
    for (int i = 0; i < 16; ++i) mr[i] = mrowS[rloc[i]];
    float mcv[4];
    if (offdiag) {
        #pragma unroll
        for (int cf = 0; cf < 4; ++cf) mcv[cf] = mcolS[cloc[cf]];
    }

    float srl[16];
    #pragma unroll
    for (int i = 0; i < 16; ++i) srl[i] = 0.f;
    float scl[4] = {0.f, 0.f, 0.f, 0.f};
    #pragma unroll
    for (int rf = 0; rf < 4; ++rf)
        #pragma unroll
        for (int cf = 0; cf < 4; ++cf)
            #pragma unroll
            for (int rg = 0; rg < 4; ++rg) {
                int i = rf * 4 + rg;
                float v = acc[rf][cf][rg];
                srl[i] += exp2f(v - mr[i]);
                if (offdiag) scl[cf] += exp2f(v - mcv[cf]);
            }
    #pragma unroll
    for (int i = 0; i < 16; ++i) rows_s[rloc[i] * 33 + grp32] = srl[i];
    if (offdiag) {
        #pragma unroll
        for (int cf = 0; cf < 4; ++cf) cols_s[cloc[cf] * 9 + grp8] = scl[cf];
    }
    __syncthreads();
    if (tid < 128) {
        float s = 0.f;
        #pragma unroll
        for (int g = 0; g < 32; ++g) s += rows_s[tid * 33 + g];
        partial[(size_t)ct * N2 + rowBase + tid] = make_float2(mrowS[tid], s);
        if (offdiag) {
            float s2 = 0.f;
            #pragma unroll
            for (int g = 0; g < 8; ++g) s2 += cols_s[tid * 9 + g];
            partial[(size_t)rt * N2 + colBase + tid] = make_float2(mcolS[tid], s2);
        }
    }
}

// ---------- merge col-tile partials -> c_id2[row] (log2 domain) ----------
__global__ __launch_bounds__(256) void mergeC(const float2* __restrict__ partial,
                                              float* __restrict__ cid) {
    int row = blockIdx.x * 256 + threadIdx.x;
    float m = NEGINF, s = 0.f;
    for (int ct = 0; ct < 64; ++ct) {
        float2 p = partial[(size_t)ct * N2 + row];
        float nm = fmaxf(m, p.x);
        s = s * exp2f(m - nm) + p.y * exp2f(p.x - nm);
        m = nm;
    }
    cid[row] = m + __log2f(s);
}

// ---------- Phase B: class-list walk, lane-parallel CE ----------
__global__ __launch_bounds__(512) void phaseB(const float* __restrict__ feat,
                                              const int* __restrict__ label,
                                              const int* __restrict__ camid,
                                              const int* __restrict__ lists,
                                              const float* __restrict__ cid_,
                                              float* __restrict__ rowloss) {
    __shared__ float listA[8][64];
    __shared__ int   listF[8][64];

    const int tid = threadIdx.x, lane = tid & 63, w = tid >> 6;
    const int row = blockIdx.x * 8 + w;
    const int rl = label[row & (N_ - 1)];
    const int rc = camid[row & (N_ - 1)];
    const float cid = cid_[row] * LN2F;       // -> natural log
    const float* fi = frow(feat, row);
    float4 fi4 = *(const float4*)(fi + lane * 4);

    const int* Lp = lists + (size_t)rl * (LCAP + 1);
    const int nmem = Lp[0];

    int cnt = 0;
    for (int e = 0; e < nmem; ++e) {
        int j = Lp[1 + e];
        int cm = (camid[j] == rc) ? 1 : 0;
        #pragma unroll
        for (int h = 0; h < 2; ++h) {
            int c = j + h * N_;
            if (c == row) continue;          // wave-uniform
            const float* fc = frow(feat, c);
            float4 v = *(const float4*)(fc + lane * 4);
            float p = fi4.x * v.x + fi4.y * v.y + fi4.z * v.z + fi4.w * v.w;
            #pragma unroll
            for (int off = 32; off >= 1; off >>= 1) p += __shfl_xor(p, off);
            if (lane == 0) { listA[w][cnt] = p * INV_TEMP; listF[w][cnt] = cm; }
            ++cnt;
        }
    }

    float a_e = (lane < cnt) ? listA[w][lane] : NEGINF;
    int   f_e = (lane < cnt) ? listF[w][lane] : 1;

    // extras LSE (label-match, cam-mismatch)
    float xa = (f_e == 0) ? a_e : NEGINF;
    float mx = xa;
    #pragma unroll
    for (int off = 32; off >= 1; off >>= 1) mx = fmaxf(mx, __shfl_xor(mx, off));
    float xe = (f_e == 0) ? __expf(xa - mx) : 0.f;
    #pragma unroll
    for (int off = 32; off >= 1; off >>= 1) xe += __shfl_xor(xe, off);
    float ccam;
    if (xe > 0.f) {
        float xl = mx + __logf(xe);
        float d = xl - cid;
        ccam = (d <= 0.f) ? cid + log1pf(__expf(d)) : xl + log1pf(__expf(-d));
    } else {
        ccam = cid;
    }

    float ti = cid - a_e;
    float termid = (ti <= 0.f) ? log1pf(__expf(ti)) : ti + log1pf(__expf(-ti));
    termid = (lane < cnt) ? termid : 0.f;
    float tc = ccam - a_e;
    float termcam = (tc <= 0.f) ? log1pf(__expf(tc)) : tc + log1pf(__expf(-tc));
    termcam = (lane < cnt && f_e) ? termcam : 0.f;
    #pragma unroll
    for (int off = 32; off >= 1; off >>= 1) {
        termid  += __shfl_xor(termid, off);
        termcam += __shfl_xor(termcam, off);
    }
    int ncam = __popcll(__ballot(lane < cnt && f_e));
    if (lane == 0)
        rowloss[row] = termid / (float)cnt + 0.5f * termcam / (float)ncam;
}

// ---------- Phase C: deterministic final reduce ----------
__global__ __launch_bounds__(256) void phaseC(const float* __restrict__ rowloss,
                                              float* __restrict__ out) {
    __shared__ float red[256];
    float s = 0.f;
    for (int i = threadIdx.x; i < N2; i += 256) s += rowloss[i];
    red[threadIdx.x] = s;
    __syncthreads();
    for (int w = 128; w > 0; w >>= 1) {
        if (threadIdx.x < w) red[threadIdx.x] += red[threadIdx.x + w];
        __syncthreads();
    }
    if (threadIdx.x == 0) out[0] = red[0] / (float)N2;
}

extern "C" void kernel_launch(void* const* d_in, const int* in_sizes, int n_in,
                              void* d_out, int out_size, void* d_ws, size_t ws_size,
                              hipStream_t stream) {
    const float* feat  = (const float*)d_in[0];
    const int*   label = (const int*)d_in[1];
    const int*   camid = (const int*)d_in[2];

    ushort* fhi = (ushort*)d_ws;                                  // 4 MB
    ushort* flo = fhi + (size_t)N2 * D_;                          // 4 MB
    float2* partial = (float2*)((char*)d_ws + 8u * 1024 * 1024);  // 4 MB
    float*  cid     = (float*)((char*)d_ws + 12u * 1024 * 1024);  // 32 KB
    float*  rowloss = cid + N2;                                   // 32 KB
    int*    lists   = (int*)(rowloss + N2);                       // 1000*33*4 B

    prepK<<<1274, 256, 0, stream>>>(feat, label, fhi, flo, lists);
    phaseA<<<2080, 256, 0, stream>>>(fhi, flo, label, partial);
    mergeC<<<32, 256, 0, stream>>>(partial, cid);
    phaseB<<<1024, 512, 0, stream>>>(feat, label, camid, lists, cid, rowloss);
    phaseC<<<1, 256, 0, stream>>>(rowloss, (float*)d_out);
}

// Round 7
// 131.555 us; speedup vs baseline: 1.3372x; 1.0079x over previous
//
#include <hip/hip_runtime.h>

typedef __attribute__((ext_vector_type(8))) short  s8v;   // 8 bf16 (4 VGPR)
typedef __attribute__((ext_vector_type(4))) float  f4v;   // MFMA accumulator

#define N_   4096
#define N2   8192
#define D_   256
#define NIDS 1000
#define LCAP 32      // max members per class

constexpr float INV_TEMP   = 10.0f;                 // 1/0.1
constexpr float K_LOG2     = 14.426950408889634f;   // 10 * log2(e)
constexpr float LN2F       = 0.6931471805599453f;
constexpr float NEGINF     = -1e30f;

__device__ __forceinline__ const float* frow(const float* f, int r) {
    return f + (size_t)(r & (N_ - 1)) * (2 * D_) + (size_t)((r >> 12) * D_);
}

__device__ __forceinline__ ushort f2bf(float x) {
    unsigned u = __float_as_uint(x);
    return (ushort)((u + 0x7FFFu + ((u >> 16) & 1u)) >> 16);   // RNE
}
__device__ __forceinline__ float bf2f(ushort b) {
    return __uint_as_float(((unsigned)b) << 16);
}

// async 16B global -> LDS (linear dest: wave-uniform base + lane*16)
__device__ __forceinline__ void gload_lds16(const void* g, void* l) {
    __builtin_amdgcn_global_load_lds(
        (const __attribute__((address_space(1))) void*)g,
        (__attribute__((address_space(3))) void*)l, 16, 0, 0);
}

// ---------- fused: convert f32 -> hi/lo bf16  +  per-class lists  + counter reset ----------
__global__ __launch_bounds__(256) void prepK(const float* __restrict__ feat,
                                             const int* __restrict__ label,
                                             ushort* __restrict__ fhi,
                                             ushort* __restrict__ flo,
                                             int* __restrict__ lists,
                                             int* __restrict__ done) {
    if (blockIdx.x < 1024) {
        int t = blockIdx.x * 256 + threadIdx.x;
        int r = t >> 5, g = t & 31;
        const float* src = frow(feat, r) + g * 8;
        float4 v0 = *(const float4*)src;
        float4 v1 = *(const float4*)(src + 4);
        float x[8] = {v0.x, v0.y, v0.z, v0.w, v1.x, v1.y, v1.z, v1.w};
        s8v h8, l8;
        #pragma unroll
        for (int i = 0; i < 8; ++i) {
            ushort h = f2bf(x[i]);
            h8[i] = (short)h;
            l8[i] = (short)f2bf(x[i] - bf2f(h));
        }
        *(s8v*)(fhi + (size_t)r * D_ + g * 8) = h8;
        *(s8v*)(flo + (size_t)r * D_ + g * 8) = l8;
    } else {
        if (blockIdx.x == 1024 && threadIdx.x == 0) *done = 0;   // reset every call
        int cls  = (blockIdx.x - 1024) * 4 + (threadIdx.x >> 6);   // 250 blocks
        int lane = threadIdx.x & 63;
        int* Lp = lists + (size_t)cls * (LCAP + 1);
        int cnt = 0;
        for (int jj = 0; jj < N_; jj += 64) {
            unsigned long long mk = __ballot(label[jj + lane] == cls);
            while (mk) {
                int b = __ffsll((unsigned long long)mk) - 1;
                mk &= mk - 1;
                if (lane == 0 && cnt < LCAP) Lp[1 + cnt] = jj + b;
                ++cnt;
            }
        }
        if (lane == 0) Lp[0] = (cnt < LCAP) ? cnt : LCAP;
    }
}

// ---------- Phase A: upper-tri 128x128, KC=32 double-buffered DMA staging ----------
__global__ __launch_bounds__(256) void phaseA(const ushort* __restrict__ fhi,
                                              const ushort* __restrict__ flo,
                                              const int* __restrict__ label,
                                              float2* __restrict__ partial) {
    __shared__ ushort panels[2][4][128][32];   // 2 buf x {Ahi,Alo,Bhi,Blo} x 8KB = 64 KB
    char* base = (char*)panels;

    const int tid  = threadIdx.x;
    const int lane = tid & 63;
    const int w    = tid >> 6;
    const int wr   = w >> 1, wc = w & 1;

    // XCD swizzle (2080 = 8*260, bijective) then upper-tri decode
    int idx = (blockIdx.x & 7) * 260 + (blockIdx.x >> 3);
    int rt = 0, rem = idx;
    while (rem >= 64 - rt) { rem -= 64 - rt; ++rt; }
    const int ct = rt + rem;
    const bool offdiag = (ct != rt);
    const int rowBase = rt * 128, colBase = ct * 128;

    f4v acc[4][4];
    #pragma unroll
    for (int i = 0; i < 4; ++i)
        #pragma unroll
        for (int j = 0; j < 4; ++j) acc[i][j] = (f4v){0.f, 0.f, 0.f, 0.f};

    // staging: wave w owns panel w. Linear LDS dest <=> pre-swizzled global src.
    // swizzle X(r) = (r&6)<<3 bytes (16B-granular: DMA src stays contiguous;
    // b128 reads land at uniform 2-way bank aliasing = free)
    const ushort* gsrc = (w & 1) ? flo : fhi;
    const int     prB  = (w < 2) ? rowBase : colBase;
    char* lpan = base + w * 8192;              // + buf*32768
    const int r4  = lane >> 2;                 // row within 16-row stripe
    const int b16 = (lane & 3) * 16;           // 16B slot in 64B row
    const size_t glane = (size_t)(prB + r4) * D_ + (size_t)((b16 ^ ((r4 & 6) << 3)) >> 1);

    // prologue: stage chunk 0 -> buf 0
    #pragma unroll
    for (int i = 0; i < 8; ++i)
        gload_lds16(gsrc + glane + (size_t)i * 16 * D_, lpan + i * 1024);
    __syncthreads();

    const int kb    = (lane >> 4) * 16;
    const int l15   = lane & 15;
    const int swzr  = (l15 & 6) << 3;
    const int aoff0 = wr * 4096 + l15 * 64 + (kb ^ swzr);
    const int boff0 = wc * 4096 + l15 * 64 + (kb ^ swzr);

    for (int kc = 0; kc < 8; ++kc) {
        const int cur = kc & 1;
        if (kc < 7) {   // stage next chunk into the other buffer; flies under compute
            const ushort* gk = gsrc + glane + (size_t)(kc + 1) * 32;
            char* lp = base + (cur ^ 1) * 32768 + w * 8192;
            #pragma unroll
            for (int i = 0; i < 8; ++i)
                gload_lds16(gk + (size_t)i * 16 * D_, lp + i * 1024);
        }

        const char* bb = base + cur * 32768;
        s8v ah[4], al[4], bh[4], bl[4];
        #pragma unroll
        for (int rf = 0; rf < 4; ++rf) {
            ah[rf] = *(const s8v*)(bb + aoff0 + rf * 1024);
            al[rf] = *(const s8v*)(bb + 8192 + aoff0 + rf * 1024);
        }
        #pragma unroll
        for (int cf = 0; cf < 4; ++cf) {
            bh[cf] = *(const s8v*)(bb + 16384 + boff0 + cf * 1024);
            bl[cf] = *(const s8v*)(bb + 24576 + boff0 + cf * 1024);
        }
        #pragma unroll
        for (int rf = 0; rf < 4; ++rf)
            #pragma unroll
            for (int cf = 0; cf < 4; ++cf) {
                acc[rf][cf] = __builtin_amdgcn_mfma_f32_16x16x32_bf16(ah[rf], bh[cf], acc[rf][cf], 0, 0, 0);
                acc[rf][cf] = __builtin_amdgcn_mfma_f32_16x16x32_bf16(al[rf], bh[cf], acc[rf][cf], 0, 0, 0);
                acc[rf][cf] = __builtin_amdgcn_mfma_f32_16x16x32_bf16(ah[rf], bl[cf], acc[rf][cf], 0, 0, 0);
            }
        __syncthreads();   // waves done reading buf[cur]; next-chunk DMA landed
    }

    // ================= epilogue (log2 domain) =================
    float* fsm    = (float*)base;
    float* rowm   = fsm;                       // [128][33]
    float* colm   = fsm + 4224;                // [128][9]
    float* mrowS  = fsm + 4224 + 1152;         // [128]
    float* mcolS  = mrowS + 128;               // [128]
    float* rows_s = mcolS + 128;               // [128][33]
    float* cols_s = rows_s + 4224;             // [128][9]

    const int grp32 = wc * 16 + l15;
    const int grp8  = wr * 4 + (lane >> 4);
    int rloc[16], cloc[4];
    int rowlab[16], collab[4];
    #pragma unroll
    for (int rf = 0; rf < 4; ++rf)
        #pragma unroll
        for (int rg = 0; rg < 4; ++rg) {
            int i = rf * 4 + rg;
            rloc[i] = wr * 64 + rf * 16 + (lane >> 4) * 4 + rg;
            rowlab[i] = label[(rowBase + rloc[i]) & (N_ - 1)];
        }
    #pragma unroll
    for (int cf = 0; cf < 4; ++cf) {
        cloc[cf] = wc * 64 + cf * 16 + l15;
        collab[cf] = label[(colBase + cloc[cf]) & (N_ - 1)];
    }

    // masked log2-logits in place (positives/diag -> -1e30)
    #pragma unroll
    for (int rf = 0; rf < 4; ++rf)
        #pragma unroll
        for (int cf = 0; cf < 4; ++cf)
            #pragma unroll
            for (int rg = 0; rg < 4; ++rg) {
                float v = acc[rf][cf][rg] * K_LOG2;
                acc[rf][cf][rg] = (collab[cf] == rowlab[rf * 4 + rg]) ? NEGINF : v;
            }

    #pragma unroll
    for (int rf = 0; rf < 4; ++rf)
        #pragma unroll
        for (int rg = 0; rg < 4; ++rg) {
            int i = rf * 4 + rg;
            float m = fmaxf(fmaxf(acc[rf][0][rg], acc[rf][1][rg]),
                            fmaxf(acc[rf][2][rg], acc[rf][3][rg]));
            rowm[rloc[i] * 33 + grp32] = m;
        }
    if (offdiag) {
        #pragma unroll
        for (int cf = 0; cf < 4; ++cf) {
            float m = NEGINF;
            #pragma unroll
            for (int rf = 0; rf < 4; ++rf)
                #pragma unroll
                for (int rg = 0; rg < 4; ++rg)
                    m = fmaxf(m, acc[rf][cf][rg]);
            colm[cloc[cf] * 9 + grp8] = m;
        }
    }
    __syncthreads();
    if (tid < 128) {
        float m = NEGINF;
        #pragma unroll
        for (int g = 0; g < 32; ++g) m = fmaxf(m, rowm[tid * 33 + g]);
        mrowS[tid] = m;
        if (offdiag) {
            float mc = NEGINF;
            #pragma unroll
            for (int g = 0; g < 8; ++g) mc = fmaxf(mc, colm[tid * 9 + g]);
            mcolS[tid] = mc;
        }
    }
    __syncthreads();

    float mr[16];
    #pragma unroll
    for (int i = 0; i < 16; ++i) mr[i] = mrowS[rloc[i]];
    float mcv[4];
    if (offdiag) {
        #pragma unroll
        for (int cf = 0; cf < 4; ++cf) mcv[cf] = mcolS[cloc[cf]];
    }

    float srl[16];
    #pragma unroll
    for (int i = 0; i < 16; ++i) srl[i] = 0.f;
    float scl[4] = {0.f, 0.f, 0.f, 0.f};
    #pragma unroll
    for (int rf = 0; rf < 4; ++rf)
        #pragma unroll
        for (int cf = 0; cf < 4; ++cf)
            #pragma unroll
            for (int rg = 0; rg < 4; ++rg) {
                int i = rf * 4 + rg;
                float v = acc[rf][cf][rg];
                srl[i] += exp2f(v - mr[i]);
                if (offdiag) scl[cf] += exp2f(v - mcv[cf]);
            }
    #pragma unroll
    for (int i = 0; i < 16; ++i) rows_s[rloc[i] * 33 + grp32] = srl[i];
    if (offdiag) {
        #pragma unroll
        for (int cf = 0; cf < 4; ++cf) cols_s[cloc[cf] * 9 + grp8] = scl[cf];
    }
    __syncthreads();
    if (tid < 128) {
        float s = 0.f;
        #pragma unroll
        for (int g = 0; g < 32; ++g) s += rows_s[tid * 33 + g];
        partial[(size_t)ct * N2 + rowBase + tid] = make_float2(mrowS[tid], s);
        if (offdiag) {
            float s2 = 0.f;
            #pragma unroll
            for (int g = 0; g < 8; ++g) s2 += cols_s[tid * 9 + g];
            partial[(size_t)rt * N2 + colBase + tid] = make_float2(mcolS[tid], s2);
        }
    }
}

// ---------- Phase B: fused partial-merge + class-list CE + last-block final ----------
__global__ __launch_bounds__(512) void phaseB(const float* __restrict__ feat,
                                              const int* __restrict__ label,
                                              const int* __restrict__ camid,
                                              const int* __restrict__ lists,
                                              const float2* __restrict__ partial,
                                              float* __restrict__ rowloss,
                                              int* __restrict__ done,
                                              float* __restrict__ out) {
    __shared__ float listA[8][64];
    __shared__ int   listF[8][64];
    __shared__ float red[512];
    __shared__ int   lastFlag;

    const int tid = threadIdx.x, lane = tid & 63, w = tid >> 6;
    const int row = blockIdx.x * 8 + w;
    const int rl = label[row & (N_ - 1)];
    const int rc = camid[row & (N_ - 1)];

    // c_id via lane-parallel merge of the 64 col-panel partials (log2 domain)
    float2 p = partial[(size_t)lane * N2 + row];
    float mm = p.x, ms = p.y;
    #pragma unroll
    for (int off = 32; off >= 1; off >>= 1) {
        float om = __shfl_xor(mm, off), os = __shfl_xor(ms, off);
        float nm = fmaxf(mm, om);
        ms = ms * exp2f(mm - nm) + os * exp2f(om - nm);
        mm = nm;
    }
    const float cid = (mm + __log2f(ms)) * LN2F;   // natural-log domain

    const float* fi = frow(feat, row);
    float4 fi4 = *(const float4*)(fi + lane * 4);

    const int* Lp = lists + (size_t)rl * (LCAP + 1);
    const int nmem = Lp[0];

    int cnt = 0;
    for (int e = 0; e < nmem; ++e) {
        int j = Lp[1 + e];
        int cm = (camid[j] == rc) ? 1 : 0;
        #pragma unroll
        for (int h = 0; h < 2; ++h) {
            int c = j + h * N_;
            if (c == row) continue;          // wave-uniform
            const float* fc = frow(feat, c);
            float4 v = *(const float4*)(fc + lane * 4);
            float pp = fi4.x * v.x + fi4.y * v.y + fi4.z * v.z + fi4.w * v.w;
            #pragma unroll
            for (int off = 32; off >= 1; off >>= 1) pp += __shfl_xor(pp, off);
            if (lane == 0) { listA[w][cnt] = pp * INV_TEMP; listF[w][cnt] = cm; }
            ++cnt;
        }
    }

    float a_e = (lane < cnt) ? listA[w][lane] : NEGINF;
    int   f_e = (lane < cnt) ? listF[w][lane] : 1;

    // extras LSE (label-match, cam-mismatch) -> c_cam
    float xa = (f_e == 0) ? a_e : NEGINF;
    float mx = xa;
    #pragma unroll
    for (int off = 32; off >= 1; off >>= 1) mx = fmaxf(mx, __shfl_xor(mx, off));
    float xe = (f_e == 0) ? __expf(xa - mx) : 0.f;
    #pragma unroll
    for (int off = 32; off >= 1; off >>= 1) xe += __shfl_xor(xe, off);
    float ccam;
    if (xe > 0.f) {
        float xl = mx + __logf(xe);
        float d = xl - cid;
        ccam = (d <= 0.f) ? cid + log1pf(__expf(d)) : xl + log1pf(__expf(-d));
    } else {
        ccam = cid;
    }

    float ti = cid - a_e;
    float termid = (ti <= 0.f) ? log1pf(__expf(ti)) : ti + log1pf(__expf(-ti));
    termid = (lane < cnt) ? termid : 0.f;
    float tc = ccam - a_e;
    float termcam = (tc <= 0.f) ? log1pf(__expf(tc)) : tc + log1pf(__expf(-tc));
    termcam = (lane < cnt && f_e) ? termcam : 0.f;
    #pragma unroll
    for (int off = 32; off >= 1; off >>= 1) {
        termid  += __shfl_xor(termid, off);
        termcam += __shfl_xor(termcam, off);
    }
    int ncam = __popcll(__ballot(lane < cnt && f_e));
    if (lane == 0)
        rowloss[row] = termid / (float)cnt + 0.5f * termcam / (float)ncam;

    // ---- last-block deterministic final reduce ----
    __syncthreads();                 // block's rowloss stores drained (vmcnt on barrier)
    if (tid == 0) {
        __threadfence();             // release
        lastFlag = (atomicAdd(done, 1) == (int)gridDim.x - 1) ? 1 : 0;
    }
    __syncthreads();
    if (lastFlag) {
        __threadfence();             // acquire
        float s = 0.f;
        const int b0 = tid * 16;
        #pragma unroll
        for (int i = 0; i < 16; ++i) s += rowloss[b0 + i];   // fixed order
        red[tid] = s;
        __syncthreads();
        for (int ww = 256; ww > 0; ww >>= 1) {
            if (tid < ww) red[tid] += red[tid + ww];
            __syncthreads();
        }
        if (tid == 0) out[0] = red[0] / (float)N2;
    }
}

extern "C" void kernel_launch(void* const* d_in, const int* in_sizes, int n_in,
                              void* d_out, int out_size, void* d_ws, size_t ws_size,
                              hipStream_t stream) {
    const float* feat  = (const float*)d_in[0];
    const int*   label = (const int*)d_in[1];
    const int*   camid = (const int*)d_in[2];

    ushort* fhi = (ushort*)d_ws;                                  // 4 MB
    ushort* flo = fhi + (size_t)N2 * D_;                          // 4 MB
    float2* partial = (float2*)((char*)d_ws + 8u * 1024 * 1024);  // 4 MB
    float*  rowloss = (float*)((char*)d_ws + 12u * 1024 * 1024);  // 32 KB
    int*    lists   = (int*)(rowloss + N2);                       // 1000*33*4 B
    int*    done    = lists + NIDS * (LCAP + 1);                  // 4 B

    prepK<<<1274, 256, 0, stream>>>(feat, label, fhi, flo, lists, done);
    phaseA<<<2080, 256, 0, stream>>>(fhi, flo, label, partial);
    phaseB<<<1024, 512, 0, stream>>>(feat, label, camid, lists, partial,
                                     rowloss, done, (float*)d_out);
}

// Round 8
// 95.475 us; speedup vs baseline: 1.8425x; 1.3779x over previous
//
#include <hip/hip_runtime.h>

typedef __attribute__((ext_vector_type(8))) _Float16 h8v;  // 8 fp16 (4 VGPR)
typedef __attribute__((ext_vector_type(8))) short    s8v;
typedef __attribute__((ext_vector_type(4))) float    f4v;  // MFMA accumulator

#define N_   4096
#define N2   8192
#define D_   256
#define NIDS 1000
#define LCAP 32

constexpr float INV_TEMP = 10.0f;                 // 1/0.1
constexpr float K_LOG2   = 14.426950408889634f;   // 10 * log2(e)
constexpr float LN2F     = 0.6931471805599453f;
constexpr float NEGINF   = -1e30f;

__device__ __forceinline__ const float* frow(const float* f, int r) {
    return f + (size_t)(r & (N_ - 1)) * (2 * D_) + (size_t)((r >> 12) * D_);
}

// async 16B global -> LDS (linear dest: wave-uniform base + lane*16)
__device__ __forceinline__ void gload_lds16(const void* g, void* l) {
    __builtin_amdgcn_global_load_lds(
        (const __attribute__((address_space(1))) void*)g,
        (__attribute__((address_space(3))) void*)l, 16, 0, 0);
}

// ---------- fused: convert f32 -> fp16  +  per-class lists  + counter reset ----------
__global__ __launch_bounds__(256) void prepK(const float* __restrict__ feat,
                                             const int* __restrict__ label,
                                             _Float16* __restrict__ f16,
                                             int* __restrict__ lists,
                                             int* __restrict__ done) {
    if (blockIdx.x < 1024) {
        int t = blockIdx.x * 256 + threadIdx.x;
        int r = t >> 5, g = t & 31;
        const float* src = frow(feat, r) + g * 8;
        float4 v0 = *(const float4*)src;
        float4 v1 = *(const float4*)(src + 4);
        float x[8] = {v0.x, v0.y, v0.z, v0.w, v1.x, v1.y, v1.z, v1.w};
        h8v h;
        #pragma unroll
        for (int i = 0; i < 8; ++i) h[i] = (_Float16)x[i];
        *(h8v*)(f16 + (size_t)r * D_ + g * 8) = h;
    } else {
        if (blockIdx.x == 1024 && threadIdx.x == 0) *done = 0;   // reset every call
        int cls  = (blockIdx.x - 1024) * 4 + (threadIdx.x >> 6);
        int lane = threadIdx.x & 63;
        int* Lp = lists + (size_t)cls * (LCAP + 1);
        int cnt = 0;
        for (int jj = 0; jj < N_; jj += 64) {
            unsigned long long mk = __ballot(label[jj + lane] == cls);
            while (mk) {
                int b = __ffsll((unsigned long long)mk) - 1;
                mk &= mk - 1;
                if (lane == 0 && cnt < LCAP) Lp[1 + cnt] = jj + b;
                ++cnt;
            }
        }
        if (lane == 0) Lp[0] = (cnt < LCAP) ? cnt : LCAP;
    }
}

// ---------- Phase A: upper-tri 128x128, fp16 single-pass, KC=32 dbuf DMA ----------
__global__ __launch_bounds__(256, 4) void phaseA(const _Float16* __restrict__ f16,
                                                 const int* __restrict__ label,
                                                 float2* __restrict__ partial) {
    __shared__ char lds[32768];   // 2 buf x (A 8KB | B 8KB)

    const int tid  = threadIdx.x;
    const int lane = tid & 63;
    const int w    = tid >> 6;
    const int wr   = w >> 1, wc = w & 1;

    // XCD swizzle (2080 = 8*260, bijective) then upper-tri decode
    int idx = (blockIdx.x & 7) * 260 + (blockIdx.x >> 3);
    int rt = 0, rem = idx;
    while (rem >= 64 - rt) { rem -= 64 - rt; ++rt; }
    const int ct = rt + rem;
    const bool offdiag = (ct != rt);
    const int rowBase = rt * 128, colBase = ct * 128;

    f4v acc[4][4];
    #pragma unroll
    for (int i = 0; i < 4; ++i)
        #pragma unroll
        for (int j = 0; j < 4; ++j) acc[i][j] = (f4v){0.f, 0.f, 0.f, 0.f};

    // staging: waves 0,1 -> A halves; 2,3 -> B halves. Linear LDS dest,
    // pre-swizzled source slot s = (l&3) ^ ((l>>3)&3)  (16B-granular XOR).
    const int prB = (w < 2) ? rowBase : colBase;
    const int ssrc = (lane & 3) ^ ((lane >> 3) & 3);
    const _Float16* gl = f16 + (size_t)(prB + (w & 1) * 64 + (lane >> 2)) * D_ + ssrc * 8;
    const int ldoff = ((w >= 2) ? 8192 : 0) + (w & 1) * 4096 + lane * 16;

    // prologue: chunk 0 -> buf 0
    #pragma unroll
    for (int i = 0; i < 4; ++i)
        gload_lds16(gl + (size_t)i * 16 * D_, lds + ldoff + i * 1024);
    __syncthreads();

    const int l15  = lane & 15;
    const int phys = ((lane >> 4) ^ ((l15 >> 1) & 3)) * 16;
    const int aoff0 = (wr * 64 + l15) * 64 + phys;
    const int boff0 = 8192 + (wc * 64 + l15) * 64 + phys;

    for (int kc = 0; kc < 8; ++kc) {
        const int cur = kc & 1;
        if (kc < 7) {
            const _Float16* gk = gl + (kc + 1) * 32;
            char* lp = lds + (cur ^ 1) * 16384 + ldoff;
            #pragma unroll
            for (int i = 0; i < 4; ++i)
                gload_lds16(gk + (size_t)i * 16 * D_, lp + i * 1024);
        }
        const char* bb = lds + cur * 16384;
        h8v a[4], b[4];
        #pragma unroll
        for (int rf = 0; rf < 4; ++rf) a[rf] = *(const h8v*)(bb + aoff0 + rf * 1024);
        #pragma unroll
        for (int cf = 0; cf < 4; ++cf) b[cf] = *(const h8v*)(bb + boff0 + cf * 1024);
        #pragma unroll
        for (int rf = 0; rf < 4; ++rf)
            #pragma unroll
            for (int cf = 0; cf < 4; ++cf)
                acc[rf][cf] = __builtin_amdgcn_mfma_f32_16x16x32_f16(a[rf], b[cf], acc[rf][cf], 0, 0, 0);
        __syncthreads();
    }

    // ================= epilogue (log2 domain), LDS reused ==================
    float* rowm  = (float*)lds;              // [128][33]  (16896 B)
    float* colm  = (float*)(lds + 16896);    // [128][9]   (4608 B)
    float* mrowS = (float*)(lds + 21504);    // [128]
    float* mcolS = (float*)(lds + 22016);    // [128]

    const int grp32 = wc * 16 + l15;
    const int grp8  = wr * 4 + (lane >> 4);
    int rloc[16], cloc[4];
    int rowlab[16], collab[4];
    #pragma unroll
    for (int rf = 0; rf < 4; ++rf)
        #pragma unroll
        for (int rg = 0; rg < 4; ++rg) {
            int i = rf * 4 + rg;
            rloc[i] = wr * 64 + rf * 16 + (lane >> 4) * 4 + rg;
            rowlab[i] = label[(rowBase + rloc[i]) & (N_ - 1)];
        }
    #pragma unroll
    for (int cf = 0; cf < 4; ++cf) {
        cloc[cf] = wc * 64 + cf * 16 + l15;
        collab[cf] = label[(colBase + cloc[cf]) & (N_ - 1)];
    }

    // masked log2-logits in place
    #pragma unroll
    for (int rf = 0; rf < 4; ++rf)
        #pragma unroll
        for (int cf = 0; cf < 4; ++cf)
            #pragma unroll
            for (int rg = 0; rg < 4; ++rg) {
                float v = acc[rf][cf][rg] * K_LOG2;
                acc[rf][cf][rg] = (collab[cf] == rowlab[rf * 4 + rg]) ? NEGINF : v;
            }

    // pass 1: maxes
    #pragma unroll
    for (int rf = 0; rf < 4; ++rf)
        #pragma unroll
        for (int rg = 0; rg < 4; ++rg) {
            float m = fmaxf(fmaxf(acc[rf][0][rg], acc[rf][1][rg]),
                            fmaxf(acc[rf][2][rg], acc[rf][3][rg]));
            rowm[rloc[rf * 4 + rg] * 33 + grp32] = m;
        }
    if (offdiag) {
        #pragma unroll
        for (int cf = 0; cf < 4; ++cf) {
            float m = NEGINF;
            #pragma unroll
            for (int rf = 0; rf < 4; ++rf)
                #pragma unroll
                for (int rg = 0; rg < 4; ++rg) m = fmaxf(m, acc[rf][cf][rg]);
            colm[cloc[cf] * 9 + grp8] = m;
        }
    }
    __syncthreads();
    if (tid < 128) {
        float m = NEGINF;
        #pragma unroll
        for (int g = 0; g < 32; ++g) m = fmaxf(m, rowm[tid * 33 + g]);
        mrowS[tid] = m;
        if (offdiag) {
            float mc = NEGINF;
            #pragma unroll
            for (int g = 0; g < 8; ++g) mc = fmaxf(mc, colm[tid * 9 + g]);
            mcolS[tid] = mc;
        }
    }
    __syncthreads();

    // pass 2: sums (reuse rowm/colm)
    #pragma unroll
    for (int rf = 0; rf < 4; ++rf)
        #pragma unroll
        for (int rg = 0; rg < 4; ++rg) {
            int i = rf * 4 + rg;
            float m = mrowS[rloc[i]];
            float s = 0.f;
            #pragma unroll
            for (int cf = 0; cf < 4; ++cf) s += exp2f(acc[rf][cf][rg] - m);
            rowm[rloc[i] * 33 + grp32] = s;
        }
    if (offdiag) {
        #pragma unroll
        for (int cf = 0; cf < 4; ++cf) {
            float m = mcolS[cloc[cf]];
            float s = 0.f;
            #pragma unroll
            for (int rf = 0; rf < 4; ++rf)
                #pragma unroll
                for (int rg = 0; rg < 4; ++rg) s += exp2f(acc[rf][cf][rg] - m);
            colm[cloc[cf] * 9 + grp8] = s;
        }
    }
    __syncthreads();
    if (tid < 128) {
        float s = 0.f;
        #pragma unroll
        for (int g = 0; g < 32; ++g) s += rowm[tid * 33 + g];
        partial[(size_t)(rowBase + tid) * 64 + ct] = make_float2(mrowS[tid], s);
        if (offdiag) {
            float s2 = 0.f;
            #pragma unroll
            for (int g = 0; g < 8; ++g) s2 += colm[tid * 9 + g];
            partial[(size_t)(colBase + tid) * 64 + rt] = make_float2(mcolS[tid], s2);
        }
    }
}

// ---------- Phase B: merge + group-parallel dots + CE + last-block final ----------
__global__ __launch_bounds__(512) void phaseB(const float* __restrict__ feat,
                                              const int* __restrict__ label,
                                              const int* __restrict__ camid,
                                              const int* __restrict__ lists,
                                              const float2* __restrict__ partial,
                                              float* __restrict__ rowloss,
                                              int* __restrict__ done,
                                              float* __restrict__ out) {
    __shared__ int   cList[8][64];
    __shared__ int   fList[8][64];
    __shared__ float pList[8][64];
    __shared__ float red[512];
    __shared__ int   lastFlag;

    const int tid = threadIdx.x, lane = tid & 63, w = tid >> 6;
    const int row = blockIdx.x * 8 + w;
    const int rl = label[row & (N_ - 1)];
    const int rc = camid[row & (N_ - 1)];

    // c_id: coalesced row-major partial + butterfly merge (log2 domain)
    float2 p = partial[(size_t)row * 64 + lane];
    float mm = p.x, ms = p.y;
    #pragma unroll
    for (int off = 32; off >= 1; off >>= 1) {
        float om = __shfl_xor(mm, off), os = __shfl_xor(ms, off);
        float nm = fmaxf(mm, om);
        ms = ms * exp2f(mm - nm) + os * exp2f(om - nm);
        mm = nm;
    }
    const float cid = (mm + __log2f(ms)) * LN2F;

    // own row slice: lane li=lane&15 covers floats [li*16, li*16+16)
    const int li = lane & 15, g = lane >> 4;
    const float4* fip = (const float4*)frow(feat, row);
    float4 fiv[4];
    #pragma unroll
    for (int k = 0; k < 4; ++k) fiv[k] = fip[li * 4 + k];

    // candidate compaction (ascending, deterministic)
    const int* Lp = lists + (size_t)rl * (LCAP + 1);
    const int nmem = Lp[0];
    int jm = (lane < 2 * nmem) ? Lp[1 + (lane >> 1)] : -1;
    int cand = jm + (lane & 1) * N_;
    bool valid = (jm >= 0) && (cand != row);
    unsigned long long mask = __ballot(valid);
    int cnt = __popcll(mask);
    int pos = __popcll(mask & ((1ull << lane) - 1ull));
    if (valid) {
        cList[w][pos] = cand;
        fList[w][pos] = (camid[jm] == rc) ? 1 : 0;
    }

    // group-parallel dots: 4 candidates per batch (16 lanes each)
    const int nb = (cnt + 3) >> 2;
    for (int b = 0; b < nb; ++b) {
        int e = b * 4 + g;
        bool act = (e < cnt);
        int c = act ? cList[w][e] : row;
        const float4* fcp = (const float4*)frow(feat, c);
        float pp = 0.f;
        #pragma unroll
        for (int k = 0; k < 4; ++k) {
            float4 v = fcp[li * 4 + k];
            pp += fiv[k].x * v.x + fiv[k].y * v.y + fiv[k].z * v.z + fiv[k].w * v.w;
        }
        #pragma unroll
        for (int off = 8; off >= 1; off >>= 1) pp += __shfl_xor(pp, off);
        if (act && li == 0) pList[w][e] = pp * INV_TEMP;
    }

    float a_e = (lane < cnt) ? pList[w][lane] : NEGINF;
    int   f_e = (lane < cnt) ? fList[w][lane] : 1;

    // extras LSE (label-match, cam-mismatch) -> c_cam
    float xa = (f_e == 0) ? a_e : NEGINF;
    float mx = xa;
    #pragma unroll
    for (int off = 32; off >= 1; off >>= 1) mx = fmaxf(mx, __shfl_xor(mx, off));
    float xe = (f_e == 0) ? __expf(xa - mx) : 0.f;
    #pragma unroll
    for (int off = 32; off >= 1; off >>= 1) xe += __shfl_xor(xe, off);
    float ccam;
    if (xe > 0.f) {
        float xl = mx + __logf(xe);
        float d = xl - cid;
        ccam = (d <= 0.f) ? cid + log1pf(__expf(d)) : xl + log1pf(__expf(-d));
    } else {
        ccam = cid;
    }

    float ti = cid - a_e;
    float termid = (ti <= 0.f) ? log1pf(__expf(ti)) : ti + log1pf(__expf(-ti));
    termid = (lane < cnt) ? termid : 0.f;
    float tc = ccam - a_e;
    float termcam = (tc <= 0.f) ? log1pf(__expf(tc)) : tc + log1pf(__expf(-tc));
    termcam = (lane < cnt && f_e) ? termcam : 0.f;
    #pragma unroll
    for (int off = 32; off >= 1; off >>= 1) {
        termid  += __shfl_xor(termid, off);
        termcam += __shfl_xor(termcam, off);
    }
    int ncam = __popcll(__ballot(lane < cnt && f_e));
    if (lane == 0)
        rowloss[row] = termid / (float)cnt + 0.5f * termcam / (float)ncam;

    // ---- last-block deterministic final reduce ----
    __syncthreads();
    if (tid == 0) {
        __threadfence();
        lastFlag = (atomicAdd(done, 1) == (int)gridDim.x - 1) ? 1 : 0;
    }
    __syncthreads();
    if (lastFlag) {
        __threadfence();
        float s = 0.f;
        const int b0 = tid * 16;
        #pragma unroll
        for (int i = 0; i < 16; ++i) s += rowloss[b0 + i];   // fixed order
        red[tid] = s;
        __syncthreads();
        for (int ww = 256; ww > 0; ww >>= 1) {
            if (tid < ww) red[tid] += red[tid + ww];
            __syncthreads();
        }
        if (tid == 0) out[0] = red[0] / (float)N2;
    }
}

extern "C" void kernel_launch(void* const* d_in, const int* in_sizes, int n_in,
                              void* d_out, int out_size, void* d_ws, size_t ws_size,
                              hipStream_t stream) {
    const float* feat  = (const float*)d_in[0];
    const int*   label = (const int*)d_in[1];
    const int*   camid = (const int*)d_in[2];

    _Float16* f16    = (_Float16*)d_ws;                              // 4 MB
    float2*   partial = (float2*)((char*)d_ws + 4u * 1024 * 1024);   // 4 MB
    float*    rowloss = (float*)((char*)d_ws + 8u * 1024 * 1024);    // 32 KB
    int*      lists   = (int*)(rowloss + N2);                        // ~132 KB
    int*      done    = lists + NIDS * (LCAP + 1);                   // 4 B

    prepK<<<1274, 256, 0, stream>>>(feat, label, f16, lists, done);
    phaseA<<<2080, 256, 0, stream>>>(f16, label, partial);
    phaseB<<<1024, 512, 0, stream>>>(feat, label, camid, lists, partial,
                                     rowloss, done, (float*)d_out);
}